// Round 1
// baseline (1376.123 us; speedup 1.0000x reference)
//
#include <hip/hip_runtime.h>
#include <math.h>

#define D 128

__device__ __forceinline__ float sigmoid_f(float u) {
    return __builtin_amdgcn_rcpf(1.0f + __expf(-u));
}
__device__ __forceinline__ float softplus_f(float v) {
    return fmaxf(v, 0.0f) + __logf(1.0f + __expf(-fabsf(v)));
}

// x[n][d] = emb[z[n]][d]
__global__ void k_embed(const int* __restrict__ z, const float* __restrict__ emb,
                        float* __restrict__ x, int N) {
    int idx = blockIdx.x * blockDim.x + threadIdx.x;
    if (idx >= N * D) return;
    int n = idx >> 7;
    int d = idx & 127;
    x[idx] = emb[z[n] * D + d];
}

// dist[e] = ||pos[row[e]] - pos[col[e]]||
__global__ void k_dist(const int* __restrict__ row, const int* __restrict__ col,
                       const float* __restrict__ pos, float* __restrict__ dist, int E) {
    int e = blockIdx.x * blockDim.x + threadIdx.x;
    if (e >= E) return;
    int r = row[e], c = col[e];
    float dx = pos[3 * r + 0] - pos[3 * c + 0];
    float dy = pos[3 * r + 1] - pos[3 * c + 1];
    float dz = pos[3 * r + 2] - pos[3 * c + 2];
    dist[e] = sqrtf(dx * dx + dy * dy + dz * dz);
}

// O = X @ W (+bias). blockIdx.y selects which of the 4 output matrices.
// Block tile 128x128, K=128 in chunks of 32. 256 threads, 8x8 per-thread tile.
__global__ __launch_bounds__(256) void k_gemm4(
        const float* __restrict__ X,
        const float* __restrict__ Wfl, const float* __restrict__ bfl,
        const float* __restrict__ Wsl, const float* __restrict__ bsl,
        float* __restrict__ Af, float* __restrict__ Bf,
        float* __restrict__ As, float* __restrict__ Bs, int N) {
    const float* W;
    const float* bias;
    float* O;
    if (blockIdx.y == 0)      { W = Wfl;         bias = bfl;     O = Af; }
    else if (blockIdx.y == 1) { W = Wfl + D * D; bias = nullptr; O = Bf; }
    else if (blockIdx.y == 2) { W = Wsl;         bias = bsl;     O = As; }
    else                      { W = Wsl + D * D; bias = nullptr; O = Bs; }

    __shared__ float Xs[128][33];   // +1 pad breaks bank conflicts on row-varying reads
    __shared__ float Wsh[32][128];

    int tid = threadIdx.x;
    int tx = tid & 15;      // col group
    int ty = tid >> 4;      // row group
    int row0 = blockIdx.x * 128;

    float acc[8][8];
    #pragma unroll
    for (int i = 0; i < 8; i++)
        #pragma unroll
        for (int j = 0; j < 8; j++) acc[i][j] = 0.0f;

    for (int kc = 0; kc < 4; ++kc) {
        int kk0 = kc * 32;
        #pragma unroll
        for (int t = tid; t < 32 * 128; t += 256) {
            int r = t >> 7, c = t & 127;
            Wsh[r][c] = W[(kk0 + r) * D + c];
        }
        #pragma unroll
        for (int t = tid; t < 128 * 32; t += 256) {
            int r = t >> 5, k = t & 31;
            Xs[r][k] = X[(size_t)(row0 + r) * D + kk0 + k];
        }
        __syncthreads();
        #pragma unroll
        for (int kk = 0; kk < 32; ++kk) {
            float a[8], b[8];
            #pragma unroll
            for (int i = 0; i < 8; i++) a[i] = Xs[ty * 8 + i][kk];
            #pragma unroll
            for (int j = 0; j < 8; j++) b[j] = Wsh[kk][tx + 16 * j];
            #pragma unroll
            for (int i = 0; i < 8; i++)
                #pragma unroll
                for (int j = 0; j < 8; j++) acc[i][j] = fmaf(a[i], b[j], acc[i][j]);
        }
        __syncthreads();
    }
    #pragma unroll
    for (int i = 0; i < 8; i++) {
        int r = row0 + ty * 8 + i;
        #pragma unroll
        for (int j = 0; j < 8; j++) {
            int c = tx + 16 * j;
            float v = acc[i][j];
            if (bias) v += bias[c];
            O[(size_t)r * D + c] = v;
        }
    }
}

// Per target node i (edges are grouped: e in [i*deg, (i+1)*deg)):
// msg = sigmoid(Af[i]+Bf[j]+dist*wfd) * softplus(As[i]+Bs[j]+dist*wsd); agg[i] = sum
__global__ __launch_bounds__(256) void k_edges(
        const int* __restrict__ row, const float* __restrict__ dist,
        const float* __restrict__ Af, const float* __restrict__ Bf,
        const float* __restrict__ As, const float* __restrict__ Bs,
        const float* __restrict__ wfd, const float* __restrict__ wsd,
        float* __restrict__ agg, int N, int deg) {
    int node = blockIdx.x * 2 + (threadIdx.x >> 7);
    if (node >= N) return;
    int d = threadIdx.x & 127;
    float af = Af[(size_t)node * D + d];
    float as_ = As[(size_t)node * D + d];
    float wf = wfd[d], ws = wsd[d];
    float acc = 0.0f;
    size_t base = (size_t)node * deg;
    #pragma unroll 4
    for (int e = 0; e < deg; e++) {
        int j = row[base + e];
        float dst = dist[base + e];
        float u = af + Bf[(size_t)j * D + d] + dst * wf;
        float v = as_ + Bs[(size_t)j * D + d] + dst * ws;
        acc += sigmoid_f(u) * softplus_f(v);
    }
    agg[(size_t)node * D + d] = acc;
}

// per-feature sum and sumsq of P[N][D] -> atomicAdd into sums/sumsq (pre-zeroed)
__global__ __launch_bounds__(256) void k_stats(const float* __restrict__ P,
        float* __restrict__ sums, float* __restrict__ sumsq, int N) {
    __shared__ float s1[256], s2[256];
    int d = threadIdx.x & 127;
    int half = threadIdx.x >> 7;
    float a = 0.0f, b = 0.0f;
    for (int r = blockIdx.x * 2 + half; r < N; r += gridDim.x * 2) {
        float v = P[(size_t)r * D + d];
        a += v;
        b += v * v;
    }
    s1[threadIdx.x] = a;
    s2[threadIdx.x] = b;
    __syncthreads();
    if (threadIdx.x < 128) {
        atomicAdd(&sums[d], s1[threadIdx.x] + s1[threadIdx.x + 128]);
        atomicAdd(&sumsq[d], s2[threadIdx.x] + s2[threadIdx.x + 128]);
    }
}

// xnew = gc*(agg-mu1)*rsqrt(var1+eps) + bc + x   (in place over agg buffer)
// also accumulate stats of xnew into sums2/sumsq2
__global__ __launch_bounds__(256) void k_bn1res(
        const float* __restrict__ sums1, const float* __restrict__ sumsq1,
        const float* __restrict__ gc, const float* __restrict__ bc,
        const float* __restrict__ x, float* __restrict__ aggxnew,
        float* __restrict__ sums2, float* __restrict__ sumsq2, int N) {
    __shared__ float s1[256], s2[256];
    int d = threadIdx.x & 127;
    int half = threadIdx.x >> 7;
    float invN = 1.0f / (float)N;
    float mu = sums1[d] * invN;
    float var = sumsq1[d] * invN - mu * mu;
    float inv = rsqrtf(var + 1e-5f);
    float g = gc[d], b = bc[d];
    float sa = 0.0f, sb = 0.0f;
    for (int r = blockIdx.x * 2 + half; r < N; r += gridDim.x * 2) {
        size_t idx = (size_t)r * D + d;
        float v = aggxnew[idx];
        float xn = g * (v - mu) * inv + b + x[idx];
        aggxnew[idx] = xn;
        sa += xn;
        sb += xn * xn;
    }
    s1[threadIdx.x] = sa;
    s2[threadIdx.x] = sb;
    __syncthreads();
    if (threadIdx.x < 128) {
        atomicAdd(&sums2[d], s1[threadIdx.x] + s1[threadIdx.x + 128]);
        atomicAdd(&sumsq2[d], s2[threadIdx.x] + s2[threadIdx.x + 128]);
    }
}

// x = relu(gn*(xnew-mu2)*rsqrt(var2+eps) + bnb)
__global__ void k_bn2relu(const float* __restrict__ sums2, const float* __restrict__ sumsq2,
        const float* __restrict__ gn, const float* __restrict__ bnb,
        const float* __restrict__ xnew, float* __restrict__ xout, int N) {
    int idx = blockIdx.x * blockDim.x + threadIdx.x;
    if (idx >= N * D) return;
    int d = idx & 127;
    float invN = 1.0f / (float)N;
    float mu = sums2[d] * invN;
    float var = sumsq2[d] * invN - mu * mu;
    float inv = rsqrtf(var + 1e-5f);
    float v = gn[d] * (xnew[idx] - mu) * inv + bnb[d];
    xout[idx] = fmaxf(v, 0.0f);
}

// global mean pool per graph (S rows each) + relu(g@W1+b1) @ W2 + b2
__global__ __launch_bounds__(256) void k_head(const float* __restrict__ x,
        const float* __restrict__ W1, const float* __restrict__ b1,
        const float* __restrict__ W2, const float* __restrict__ b2,
        float* __restrict__ out, int S) {
    __shared__ float gmean[D];
    __shared__ float red[256];
    int g = blockIdx.x;
    int d = threadIdx.x & 127;
    int half = threadIdx.x >> 7;
    float s = 0.0f;
    size_t rbase = (size_t)g * S;
    for (int r = half; r < S; r += 2) s += x[(rbase + r) * D + d];
    red[threadIdx.x] = s;
    __syncthreads();
    if (threadIdx.x < 128) gmean[d] = (red[threadIdx.x] + red[threadIdx.x + 128]) / (float)S;
    __syncthreads();
    float val = 0.0f;
    if (threadIdx.x < 128) {
        float h = b1[d];
        #pragma unroll 8
        for (int k = 0; k < D; k++) h = fmaf(gmean[k], W1[k * D + d], h);
        h = fmaxf(h, 0.0f);
        val = h * W2[d];
    }
    red[threadIdx.x] = val;
    __syncthreads();
    for (int st = 128; st > 0; st >>= 1) {
        if (threadIdx.x < st) red[threadIdx.x] += red[threadIdx.x + st];
        __syncthreads();
    }
    if (threadIdx.x == 0) out[g] = red[0] + b2[0];
}

extern "C" void kernel_launch(void* const* d_in, const int* in_sizes, int n_in,
                              void* d_out, int out_size, void* d_ws, size_t ws_size,
                              hipStream_t stream) {
    const int*   z    = (const int*)d_in[0];
    const float* pos  = (const float*)d_in[1];
    const int*   eidx = (const int*)d_in[3];
    const float* emb  = (const float*)d_in[4];
    const float* Wf   = (const float*)d_in[5];
    const float* bf   = (const float*)d_in[6];
    const float* Ws   = (const float*)d_in[7];
    const float* bs   = (const float*)d_in[8];
    const float* gc   = (const float*)d_in[9];
    const float* bc   = (const float*)d_in[10];
    const float* gn   = (const float*)d_in[11];
    const float* bnb  = (const float*)d_in[12];
    const float* W1   = (const float*)d_in[13];
    const float* b1   = (const float*)d_in[14];
    const float* W2   = (const float*)d_in[15];
    const float* b2   = (const float*)d_in[16];

    int N = in_sizes[0];
    int E = in_sizes[3] / 2;
    int L = in_sizes[6] / D;
    int deg = E / N;
    int S = N / out_size;

    const int* row = eidx;
    const int* col = eidx + E;

    float* ws = (float*)d_ws;
    size_t nd = (size_t)N * D;
    float* x    = ws;
    float* Af   = x + nd;
    float* Bf   = Af + nd;
    float* As   = Bf + nd;
    float* Bs   = As + nd;
    float* agg  = Bs + nd;      // also reused as xnew (in-place)
    float* dist = agg + nd;
    float* stats = dist + E;    // L * 512 floats: [sums1|sumsq1|sums2|sumsq2] per layer

    hipMemsetAsync(stats, 0, (size_t)L * 512 * sizeof(float), stream);

    k_embed<<<(N * D + 255) / 256, 256, 0, stream>>>(z, emb, x, N);
    k_dist<<<(E + 255) / 256, 256, 0, stream>>>(row, col, pos, dist, E);

    for (int l = 0; l < L; ++l) {
        const float* Wfl = Wf + (size_t)l * 257 * D;
        const float* Wsl = Ws + (size_t)l * 257 * D;
        float* st = stats + (size_t)l * 512;
        k_gemm4<<<dim3(N / 128, 4), 256, 0, stream>>>(x, Wfl, bf + l * D, Wsl, bs + l * D,
                                                      Af, Bf, As, Bs, N);
        k_edges<<<N / 2, 256, 0, stream>>>(row, dist, Af, Bf, As, Bs,
                                           Wfl + 256 * D, Wsl + 256 * D, agg, N, deg);
        k_stats<<<256, 256, 0, stream>>>(agg, st, st + 128, N);
        k_bn1res<<<256, 256, 0, stream>>>(st, st + 128, gc + l * D, bc + l * D,
                                          x, agg, st + 256, st + 384, N);
        k_bn2relu<<<(N * D + 255) / 256, 256, 0, stream>>>(st + 256, st + 384,
                                                           gn + l * D, bnb + l * D, agg, x, N);
    }
    k_head<<<out_size, 256, 0, stream>>>(x, W1, b1, W2, b2, (float*)d_out, S);
}

// Round 2
// 983.890 us; speedup vs baseline: 1.3987x; 1.3987x over previous
//
#include <hip/hip_runtime.h>
#include <math.h>

#define D 128

typedef short bf16x8 __attribute__((ext_vector_type(8)));
typedef float f32x4 __attribute__((ext_vector_type(4)));

__device__ __forceinline__ unsigned short f2bf(float f) {
    unsigned int u = __float_as_uint(f);
    u += 0x7fff + ((u >> 16) & 1);   // round-to-nearest-even
    return (unsigned short)(u >> 16);
}
__device__ __forceinline__ float bf2f(unsigned short h) {
    return __uint_as_float(((unsigned int)h) << 16);
}
__device__ __forceinline__ bf16x8 load_bf8(const unsigned short* p) {
    return __builtin_bit_cast(bf16x8, *reinterpret_cast<const uint4*>(p));
}

__device__ __forceinline__ float sigmoid_f(float u) {
    return __builtin_amdgcn_rcpf(1.0f + __expf(-u));
}
__device__ __forceinline__ float softplus_f(float v) {
    return fmaxf(v, 0.0f) + __logf(1.0f + __expf(-fabsf(v)));
}

// x[n][d] = emb[z[n]][d]; also emit bf16 hi/lo split of x
__global__ void k_embed(const int* __restrict__ z, const float* __restrict__ emb,
                        float* __restrict__ x, unsigned short* __restrict__ xh,
                        unsigned short* __restrict__ xl, int N) {
    int idx = blockIdx.x * blockDim.x + threadIdx.x;
    if (idx >= N * D) return;
    int n = idx >> 7;
    int d = idx & 127;
    float v = emb[z[n] * D + d];
    x[idx] = v;
    unsigned short h = f2bf(v);
    xh[idx] = h;
    xl[idx] = f2bf(v - bf2f(h));
}

// dist[e] = ||pos[row[e]] - pos[col[e]]||
__global__ void k_dist(const int* __restrict__ row, const int* __restrict__ col,
                       const float* __restrict__ pos, float* __restrict__ dist, int E) {
    int e = blockIdx.x * blockDim.x + threadIdx.x;
    if (e >= E) return;
    int r = row[e], c = col[e];
    float dx = pos[3 * r + 0] - pos[3 * c + 0];
    float dy = pos[3 * r + 1] - pos[3 * c + 1];
    float dz = pos[3 * r + 2] - pos[3 * c + 2];
    dist[e] = sqrtf(dx * dx + dy * dy + dz * dz);
}

// Pre-transpose + bf16 hi/lo split all layer weights:
// Wt[l][mat][n][k] (mat: 0=Af,1=Bf,2=As,3=Bs), from Wf/Ws[l][(mat&1)*128+k][n]
__global__ void k_cvtW(const float* __restrict__ Wf, const float* __restrict__ Ws,
                       unsigned short* __restrict__ Wth, unsigned short* __restrict__ Wtl,
                       int L) {
    int idx = blockIdx.x * blockDim.x + threadIdx.x;
    if (idx >= L * 4 * D * D) return;
    int k = idx & 127;
    int n = (idx >> 7) & 127;
    int mat = (idx >> 14) & 3;
    int l = idx >> 16;
    const float* src = (mat < 2) ? Wf : Ws;
    float v = src[(size_t)l * 257 * D + (size_t)((mat & 1) * D + k) * D + n];
    unsigned short h = f2bf(v);
    Wth[idx] = h;
    Wtl[idx] = f2bf(v - bf2f(h));
}

// Split-bf16 MFMA GEMM: O[mat] = X @ W[mat] (+bias), X:[N][128], W^T stored [n][k].
// Block = 4 waves (2x2), 128x128 tile; wave = 64x64; no LDS, all operands L2/L3-hot.
__global__ __launch_bounds__(256) void k_gemm_mfma(
        const unsigned short* __restrict__ Xh, const unsigned short* __restrict__ Xl,
        const unsigned short* __restrict__ Wth, const unsigned short* __restrict__ Wtl,
        const float* __restrict__ bfl, const float* __restrict__ bsl,
        float* __restrict__ Af, float* __restrict__ Bf,
        float* __restrict__ As, float* __restrict__ Bs) {
    int mat = blockIdx.y;
    float* O = (mat == 0) ? Af : (mat == 1) ? Bf : (mat == 2) ? As : Bs;
    const float* bias = (mat == 0) ? bfl : (mat == 2) ? bsl : nullptr;
    const unsigned short* Wh = Wth + (size_t)mat * D * D;
    const unsigned short* Wl = Wtl + (size_t)mat * D * D;

    int wave = threadIdx.x >> 6;
    int lane = threadIdx.x & 63;
    int r16 = lane & 15;
    int kg = lane >> 4;
    int row0 = blockIdx.x * 128 + (wave >> 1) * 64;
    int wc = (wave & 1) * 64;

    f32x4 acc[4][4];
    #pragma unroll
    for (int m = 0; m < 4; m++)
        #pragma unroll
        for (int n = 0; n < 4; n++) acc[m][n] = (f32x4){0.f, 0.f, 0.f, 0.f};

    #pragma unroll
    for (int ks = 0; ks < 4; ++ks) {
        int k0 = ks * 32 + kg * 8;
        bf16x8 ah[4], al[4], bh[4], bl[4];
        #pragma unroll
        for (int m = 0; m < 4; m++) {
            size_t off = (size_t)(row0 + m * 16 + r16) * D + k0;
            ah[m] = load_bf8(Xh + off);
            al[m] = load_bf8(Xl + off);
        }
        #pragma unroll
        for (int n = 0; n < 4; n++) {
            size_t off = (size_t)(wc + n * 16 + r16) * D + k0;
            bh[n] = load_bf8(Wh + off);
            bl[n] = load_bf8(Wl + off);
        }
        #pragma unroll
        for (int m = 0; m < 4; m++)
            #pragma unroll
            for (int n = 0; n < 4; n++) {
                acc[m][n] = __builtin_amdgcn_mfma_f32_16x16x32_bf16(ah[m], bh[n], acc[m][n], 0, 0, 0);
                acc[m][n] = __builtin_amdgcn_mfma_f32_16x16x32_bf16(al[m], bh[n], acc[m][n], 0, 0, 0);
                acc[m][n] = __builtin_amdgcn_mfma_f32_16x16x32_bf16(ah[m], bl[n], acc[m][n], 0, 0, 0);
            }
    }

    // C/D layout (m89-verified): col = lane&15, row = (lane>>4)*4 + reg
    #pragma unroll
    for (int n = 0; n < 4; n++) {
        int col = wc + n * 16 + r16;
        float bv = bias ? bias[col] : 0.0f;
        #pragma unroll
        for (int m = 0; m < 4; m++) {
            int rbase = row0 + m * 16 + kg * 4;
            #pragma unroll
            for (int r = 0; r < 4; r++)
                O[(size_t)(rbase + r) * D + col] = acc[m][n][r] + bv;
        }
    }
}

// Per target node i (edges grouped: e in [i*deg,(i+1)*deg)):
// msg = sigmoid(Af[i]+Bf[j]+dist*wfd) * softplus(As[i]+Bs[j]+dist*wsd); agg[i]=sum
__global__ __launch_bounds__(256) void k_edges(
        const int* __restrict__ row, const float* __restrict__ dist,
        const float* __restrict__ Af, const float* __restrict__ Bf,
        const float* __restrict__ As, const float* __restrict__ Bs,
        const float* __restrict__ wfd, const float* __restrict__ wsd,
        float* __restrict__ agg, int N, int deg) {
    int node = blockIdx.x * 2 + (threadIdx.x >> 7);
    if (node >= N) return;
    int d = threadIdx.x & 127;
    float af = Af[(size_t)node * D + d];
    float as_ = As[(size_t)node * D + d];
    float wf = wfd[d], ws = wsd[d];
    float acc = 0.0f;
    size_t base = (size_t)node * deg;
    #pragma unroll 4
    for (int e = 0; e < deg; e++) {
        int j = row[base + e];
        float dst = dist[base + e];
        float u = af + Bf[(size_t)j * D + d] + dst * wf;
        float v = as_ + Bs[(size_t)j * D + d] + dst * ws;
        acc += sigmoid_f(u) * softplus_f(v);
    }
    agg[(size_t)node * D + d] = acc;
}

// per-feature sum and sumsq of P[N][D] -> atomicAdd into sums/sumsq (pre-zeroed)
__global__ __launch_bounds__(256) void k_stats(const float* __restrict__ P,
        float* __restrict__ sums, float* __restrict__ sumsq, int N) {
    __shared__ float s1[256], s2[256];
    int d = threadIdx.x & 127;
    int half = threadIdx.x >> 7;
    float a = 0.0f, b = 0.0f;
    for (int r = blockIdx.x * 2 + half; r < N; r += gridDim.x * 2) {
        float v = P[(size_t)r * D + d];
        a += v;
        b += v * v;
    }
    s1[threadIdx.x] = a;
    s2[threadIdx.x] = b;
    __syncthreads();
    if (threadIdx.x < 128) {
        atomicAdd(&sums[d], s1[threadIdx.x] + s1[threadIdx.x + 128]);
        atomicAdd(&sumsq[d], s2[threadIdx.x] + s2[threadIdx.x + 128]);
    }
}

// xnew = gc*(agg-mu1)*rsqrt(var1+eps) + bc + x (in place), accumulate stats of xnew
__global__ __launch_bounds__(256) void k_bn1res(
        const float* __restrict__ sums1, const float* __restrict__ sumsq1,
        const float* __restrict__ gc, const float* __restrict__ bc,
        const float* __restrict__ x, float* __restrict__ aggxnew,
        float* __restrict__ sums2, float* __restrict__ sumsq2, int N) {
    __shared__ float s1[256], s2[256];
    int d = threadIdx.x & 127;
    int half = threadIdx.x >> 7;
    float invN = 1.0f / (float)N;
    float mu = sums1[d] * invN;
    float var = sumsq1[d] * invN - mu * mu;
    float inv = rsqrtf(var + 1e-5f);
    float g = gc[d], b = bc[d];
    float sa = 0.0f, sb = 0.0f;
    for (int r = blockIdx.x * 2 + half; r < N; r += gridDim.x * 2) {
        size_t idx = (size_t)r * D + d;
        float v = aggxnew[idx];
        float xn = g * (v - mu) * inv + b + x[idx];
        aggxnew[idx] = xn;
        sa += xn;
        sb += xn * xn;
    }
    s1[threadIdx.x] = sa;
    s2[threadIdx.x] = sb;
    __syncthreads();
    if (threadIdx.x < 128) {
        atomicAdd(&sums2[d], s1[threadIdx.x] + s1[threadIdx.x + 128]);
        atomicAdd(&sumsq2[d], s2[threadIdx.x] + s2[threadIdx.x + 128]);
    }
}

// x = relu(gn*(xnew-mu2)*rsqrt(var2+eps) + bnb); also emit bf16 hi/lo split of x
__global__ void k_bn2relu(const float* __restrict__ sums2, const float* __restrict__ sumsq2,
        const float* __restrict__ gn, const float* __restrict__ bnb,
        const float* __restrict__ xnew, float* __restrict__ xout,
        unsigned short* __restrict__ xh, unsigned short* __restrict__ xl, int N) {
    int idx = blockIdx.x * blockDim.x + threadIdx.x;
    if (idx >= N * D) return;
    int d = idx & 127;
    float invN = 1.0f / (float)N;
    float mu = sums2[d] * invN;
    float var = sumsq2[d] * invN - mu * mu;
    float inv = rsqrtf(var + 1e-5f);
    float v = gn[d] * (xnew[idx] - mu) * inv + bnb[d];
    v = fmaxf(v, 0.0f);
    xout[idx] = v;
    unsigned short h = f2bf(v);
    xh[idx] = h;
    xl[idx] = f2bf(v - bf2f(h));
}

// global mean pool per graph + relu(g@W1+b1) @ W2 + b2
__global__ __launch_bounds__(256) void k_head(const float* __restrict__ x,
        const float* __restrict__ W1, const float* __restrict__ b1,
        const float* __restrict__ W2, const float* __restrict__ b2,
        float* __restrict__ out, int S) {
    __shared__ float gmean[D];
    __shared__ float red[256];
    int g = blockIdx.x;
    int d = threadIdx.x & 127;
    int half = threadIdx.x >> 7;
    float s = 0.0f;
    size_t rbase = (size_t)g * S;
    for (int r = half; r < S; r += 2) s += x[(rbase + r) * D + d];
    red[threadIdx.x] = s;
    __syncthreads();
    if (threadIdx.x < 128) gmean[d] = (red[threadIdx.x] + red[threadIdx.x + 128]) / (float)S;
    __syncthreads();
    float val = 0.0f;
    if (threadIdx.x < 128) {
        float h = b1[d];
        #pragma unroll 8
        for (int k = 0; k < D; k++) h = fmaf(gmean[k], W1[k * D + d], h);
        h = fmaxf(h, 0.0f);
        val = h * W2[d];
    }
    red[threadIdx.x] = val;
    __syncthreads();
    for (int st = 128; st > 0; st >>= 1) {
        if (threadIdx.x < st) red[threadIdx.x] += red[threadIdx.x + st];
        __syncthreads();
    }
    if (threadIdx.x == 0) out[g] = red[0] + b2[0];
}

extern "C" void kernel_launch(void* const* d_in, const int* in_sizes, int n_in,
                              void* d_out, int out_size, void* d_ws, size_t ws_size,
                              hipStream_t stream) {
    const int*   z    = (const int*)d_in[0];
    const float* pos  = (const float*)d_in[1];
    const int*   eidx = (const int*)d_in[3];
    const float* emb  = (const float*)d_in[4];
    const float* Wf   = (const float*)d_in[5];
    const float* bf   = (const float*)d_in[6];
    const float* Ws   = (const float*)d_in[7];
    const float* bs   = (const float*)d_in[8];
    const float* gc   = (const float*)d_in[9];
    const float* bc   = (const float*)d_in[10];
    const float* gn   = (const float*)d_in[11];
    const float* bnb  = (const float*)d_in[12];
    const float* W1   = (const float*)d_in[13];
    const float* b1   = (const float*)d_in[14];
    const float* W2   = (const float*)d_in[15];
    const float* b2   = (const float*)d_in[16];

    int N = in_sizes[0];
    int E = in_sizes[3] / 2;
    int L = in_sizes[6] / D;
    int deg = E / N;
    int S = N / out_size;

    const int* row = eidx;
    const int* col = eidx + E;

    float* ws = (float*)d_ws;
    size_t nd = (size_t)N * D;
    float* x    = ws;
    float* Af   = x + nd;
    float* Bf   = Af + nd;
    float* As   = Bf + nd;
    float* Bs   = As + nd;
    float* agg  = Bs + nd;      // also reused as xnew (in-place)
    float* dist = agg + nd;
    unsigned short* xh  = (unsigned short*)(dist + E);
    unsigned short* xl  = xh + nd;
    unsigned short* Wth = xl + nd;                       // L*4*128*128 bf16
    unsigned short* Wtl = Wth + (size_t)L * 4 * D * D;
    float* stats = (float*)(Wtl + (size_t)L * 4 * D * D);  // L*512 floats

    hipMemsetAsync(stats, 0, (size_t)L * 512 * sizeof(float), stream);

    k_cvtW<<<(L * 4 * D * D + 255) / 256, 256, 0, stream>>>(Wf, Ws, Wth, Wtl, L);
    k_embed<<<(N * D + 255) / 256, 256, 0, stream>>>(z, emb, x, xh, xl, N);
    k_dist<<<(E + 255) / 256, 256, 0, stream>>>(row, col, pos, dist, E);

    for (int l = 0; l < L; ++l) {
        const float* Wfl = Wf + (size_t)l * 257 * D;
        const float* Wsl = Ws + (size_t)l * 257 * D;
        float* st = stats + (size_t)l * 512;
        k_gemm_mfma<<<dim3(N / 128, 4), 256, 0, stream>>>(
            xh, xl, Wth + (size_t)l * 4 * D * D, Wtl + (size_t)l * 4 * D * D,
            bf + l * D, bs + l * D, Af, Bf, As, Bs);
        k_edges<<<N / 2, 256, 0, stream>>>(row, dist, Af, Bf, As, Bs,
                                           Wfl + 256 * D, Wsl + 256 * D, agg, N, deg);
        k_stats<<<256, 256, 0, stream>>>(agg, st, st + 128, N);
        k_bn1res<<<256, 256, 0, stream>>>(st, st + 128, gc + l * D, bc + l * D,
                                          x, agg, st + 256, st + 384, N);
        k_bn2relu<<<(N * D + 255) / 256, 256, 0, stream>>>(st + 256, st + 384,
                                                           gn + l * D, bnb + l * D, agg, x, xh, xl, N);
    }
    k_head<<<out_size, 256, 0, stream>>>(x, W1, b1, W2, b2, (float*)d_out, S);
}